// Round 18
// baseline (154.126 us; speedup 1.0000x reference)
//
#include <hip/hip_runtime.h>

#define NNODE 50000
#define NEDGE 800000
#define NBUCKET 196         // ceil(50000 / 256), bucket = dst >> 8
#define NPB 256             // nodes per bucket
#define EPB 3125            // NEDGE / 256 edges per producer block
#define G1BLK 782           // ceil(50000/64) GEMM1 tiles

typedef __attribute__((ext_vector_type(8))) unsigned short ushort8v;

__device__ inline unsigned short f2bf(float f) {           // round-to-nearest-even
    unsigned int u = __float_as_uint(f);
    u += 0x7FFFu + ((u >> 16) & 1u);
    return (unsigned short)(u >> 16);
}
__device__ inline float bf2f(unsigned short h) {
    return __uint_as_float((unsigned int)h << 16);
}
__device__ inline float bfLO(unsigned int u) { return __uint_as_float(u << 16); }
__device__ inline float bfHI(unsigned int u) { return __uint_as_float(u & 0xFFFF0000u); }

// ========== merged: edge histogram (blocks 0..255) ∥ GEMM1 (256..1037) =====
// Fully independent (GEMM1 writes RAW XW, no dinv dependency).

__global__ __launch_bounds__(256)
void k_hist_gemm1(const int* __restrict__ dst, int* __restrict__ hist_g,
                  const float* __restrict__ x, const float* __restrict__ W1,
                  unsigned short* __restrict__ XWs) {
    __shared__ float Xt[128 * 68];
    __shared__ float Ws[128 * 64];
    __shared__ int h[NBUCKET];
    const int tid = threadIdx.x, bid = blockIdx.x;

    if (bid < 256) {                      // ---- histogram chunk ----
        const int e0 = bid * EPB;
        if (tid < NBUCKET) h[tid] = 0;
        __syncthreads();
        for (int i = tid; i < EPB; i += 256)
            atomicAdd(&h[dst[e0 + i] >> 8], 1);
        __syncthreads();
        if (tid < NBUCKET) hist_g[tid * 256 + bid] = h[tid];
        return;
    }

    // ---- GEMM1 tile: 64 rows x 64 cols, FIN=128, RAW output ----
    const int r0 = (bid - 256) * 64;

    for (int idx = tid; idx < 128 * 64; idx += 256)
        Ws[idx] = W1[idx];

    for (int idx = tid; idx < 64 * 32; idx += 256) {
        int r_lo = idx & 7;
        int c = (idx >> 3) & 31;
        int r = ((idx >> 8) << 3) + r_lo;
        int rr = r0 + r; if (rr >= NNODE) rr = NNODE - 1;
        float4 v = *(const float4*)(x + (size_t)rr * 128 + c * 4);
        Xt[(4 * c + 0) * 68 + r] = v.x;
        Xt[(4 * c + 1) * 68 + r] = v.y;
        Xt[(4 * c + 2) * 68 + r] = v.z;
        Xt[(4 * c + 3) * 68 + r] = v.w;
    }
    __syncthreads();

    const int cg = tid & 15;
    const int rg = tid >> 4;

    float acc[4][4] = {};
#pragma unroll 4
    for (int k = 0; k < 128; ++k) {
        float4 xv = *(const float4*)&Xt[k * 68 + 4 * rg];
        float4 wv = *(const float4*)&Ws[k * 64 + 4 * cg];
#pragma unroll
        for (int i = 0; i < 4; ++i) {
            float xi = (i == 0) ? xv.x : (i == 1) ? xv.y : (i == 2) ? xv.z : xv.w;
            acc[i][0] = fmaf(xi, wv.x, acc[i][0]);
            acc[i][1] = fmaf(xi, wv.y, acc[i][1]);
            acc[i][2] = fmaf(xi, wv.z, acc[i][2]);
            acc[i][3] = fmaf(xi, wv.w, acc[i][3]);
        }
    }

#pragma unroll
    for (int i = 0; i < 4; ++i) {
        int row = r0 + 4 * rg + i;
        if (row < NNODE) {
            ushort4 o = { f2bf(acc[i][0]), f2bf(acc[i][1]), f2bf(acc[i][2]), f2bf(acc[i][3]) };
            *(ushort4*)(XWs + (size_t)row * 64 + 4 * cg) = o;
        }
    }
}

// ====== merged scan+scatter: each chunk derives its own bases from hist_g ===
// Thread t (t<NBUCKET) walks hist_g[t*256 + 0..255]: records prefix at p==pb
// (this chunk's within-bucket offset) and the total (bucket size). Block 0
// publishes colsum for k_bucketB2. Then LDS-scan bucket sizes -> bucket bases,
// then scatter packed edges.

__global__ __launch_bounds__(256)
void k_scan_scatter(const int* __restrict__ src, const int* __restrict__ dst,
                    const int* __restrict__ hist_g, int* __restrict__ colsum,
                    unsigned int* __restrict__ bucketed) {
    __shared__ int cs[256];
    __shared__ int cur[NBUCKET];
    const int tid = threadIdx.x, pb = blockIdx.x, e0 = pb * EPB;

    int bsize = 0, mybase = 0;
    if (tid < NBUCKET) {
        const int* hrow = hist_g + tid * 256;
        int run = 0;
        for (int p = 0; p < 256; ++p) {
            if (p == pb) mybase = run;
            run += hrow[p];
        }
        bsize = run;
        if (pb == 0) colsum[tid] = run;
    }
    cs[tid] = (tid < NBUCKET) ? bsize : 0;
    __syncthreads();
#pragma unroll
    for (int off = 1; off < 256; off <<= 1) {
        int a = (tid >= off) ? cs[tid - off] : 0;
        __syncthreads();
        cs[tid] += a;
        __syncthreads();
    }
    if (tid < NBUCKET) {
        int bb = (tid == 0) ? 0 : cs[tid - 1];       // exclusive bucket base
        cur[tid] = bb + mybase;
    }
    __syncthreads();

    for (int i = tid; i < EPB; i += 256) {
        int d = dst[e0 + i], s = src[e0 + i];
        int pos = atomicAdd(&cur[d >> 8], 1);
        bucketed[pos] = ((unsigned int)d << 16) | (unsigned int)s;
    }
}

// ---------------- Pass B: per-bucket fine CSR (contiguous reads) ----------

__device__ inline void scan_colsum(const int* __restrict__ colsum, int* cs, int tid) {
    cs[tid] = (tid < NBUCKET) ? colsum[tid] : 0;
    __syncthreads();
#pragma unroll
    for (int off = 1; off < 256; off <<= 1) {
        int a = (tid >= off) ? cs[tid - off] : 0;
        __syncthreads();
        cs[tid] += a;
        __syncthreads();
    }
}

__global__ __launch_bounds__(256) void k_bucketB2(const unsigned int* __restrict__ bucketed,
                          const int* __restrict__ colsum, int* __restrict__ rowstart,
                          unsigned short* __restrict__ csr_src, float* __restrict__ dinv) {
    __shared__ int cs[256];
    __shared__ int cnt[NPB];
    __shared__ int ex[NPB];
    __shared__ int cur[NPB];
    const int tid = threadIdx.x, b = blockIdx.x;
    scan_colsum(colsum, cs, tid);
    const int base_out = (b == 0) ? 0 : cs[b - 1];
    const int end_out  = cs[b];

    cnt[tid] = 0;
    __syncthreads();
    for (int i = base_out + tid; i < end_out; i += 256)
        atomicAdd(&cnt[(bucketed[i] >> 16) & 255], 1);
    __syncthreads();

    int v = cnt[tid];
    ex[tid] = v;
    __syncthreads();
#pragma unroll
    for (int off = 1; off < 256; off <<= 1) {
        int a = (tid >= off) ? ex[tid - off] : 0;
        __syncthreads();
        ex[tid] += a;
        __syncthreads();
    }
    int excl = ex[tid] - v;
    int node = (b << 8) + tid;
    cur[tid] = base_out + excl;
    if (node < NNODE) {
        rowstart[node] = base_out + excl;
        dinv[node] = rsqrtf((float)v + 1.0f);
    }
    if (b == 0 && tid == 0) rowstart[NNODE] = NEDGE;
    __syncthreads();

    for (int i = base_out + tid; i < end_out; i += 256) {
        unsigned int u = bucketed[i];
        int pos = atomicAdd(&cur[(u >> 16) & 255], 1);
        csr_src[pos] = (unsigned short)(u & 0xFFFFu);
    }
}

// ---------------- GEMM + prescale (layers 2,3): bf16 in, bf16 out ----------

template<int FIN, int FOUT>
__launch_bounds__(256)
__global__ void k_gemm_prescale(const unsigned short* __restrict__ X, const float* __restrict__ W,
                                const float* __restrict__ dinv, unsigned short* __restrict__ XWs) {
    __shared__ float Xt[FIN * 68];
    __shared__ float Ws[FIN * 64];

    const int tid = threadIdx.x;
    const int r0 = blockIdx.x * 64;

    for (int idx = tid; idx < FIN * 64; idx += 256) {
        int k = idx >> 6, c = idx & 63;
        Ws[idx] = (c < FOUT) ? W[k * FOUT + c] : 0.0f;
    }

    constexpr int CH = FIN / 8;
    constexpr int CSH = (FIN == 128) ? 4 : 3;
    for (int idx = tid; idx < 64 * CH; idx += 256) {
        int r_lo = idx & 7;
        int c = (idx >> 3) & (CH - 1);
        int r = ((idx >> (3 + CSH)) << 3) + r_lo;
        int rr = r0 + r; if (rr >= NNODE) rr = NNODE - 1;
        ushort8v v = *(const ushort8v*)(X + (size_t)rr * FIN + c * 8);
#pragma unroll
        for (int t = 0; t < 8; ++t)
            Xt[(8 * c + t) * 68 + r] = bf2f(v[t]);
    }
    __syncthreads();

    const int cg = tid & 15;
    const int rg = tid >> 4;

    float acc[4][4] = {};
#pragma unroll 4
    for (int k = 0; k < FIN; ++k) {
        float4 xv = *(const float4*)&Xt[k * 68 + 4 * rg];
        float4 wv = *(const float4*)&Ws[k * 64 + 4 * cg];
#pragma unroll
        for (int i = 0; i < 4; ++i) {
            float xi = (i == 0) ? xv.x : (i == 1) ? xv.y : (i == 2) ? xv.z : xv.w;
            acc[i][0] = fmaf(xi, wv.x, acc[i][0]);
            acc[i][1] = fmaf(xi, wv.y, acc[i][1]);
            acc[i][2] = fmaf(xi, wv.z, acc[i][2]);
            acc[i][3] = fmaf(xi, wv.w, acc[i][3]);
        }
    }

    if (4 * cg + 4 <= FOUT) {
#pragma unroll
        for (int i = 0; i < 4; ++i) {
            int row = r0 + 4 * rg + i;
            if (row < NNODE) {
                float dv = dinv[row];
                ushort4 o = { f2bf(acc[i][0] * dv), f2bf(acc[i][1] * dv),
                              f2bf(acc[i][2] * dv), f2bf(acc[i][3] * dv) };
                *(ushort4*)(XWs + (size_t)row * FOUT + 4 * cg) = o;
            }
        }
    }
}

// ---------------- CSR aggregate + finalize: 2-deep MLP unroll --------------

template<int F, bool RELU, bool OUTBF, bool EDGE_DINV>
__launch_bounds__(256)
__global__ void k_aggregate(const unsigned short* __restrict__ XWs, const int* __restrict__ rowstart,
                            const unsigned short* __restrict__ csr_src, const float* __restrict__ dinv,
                            const float* __restrict__ b, void* __restrict__ outp) {
    constexpr int NQ = F / 8;
    const int wid  = threadIdx.x >> 6;
    const int lane = threadIdx.x & 63;
    const int g = lane >> 3;
    const int q = lane & 7;
    const int d = blockIdx.x * 4 + wid;
    if (d >= NNODE) return;

    const int beg = rowstart[d];
    const int end = rowstart[d + 1];
    const bool qa = (q < NQ);

    float acc[8] = {};

    for (int base = beg; base < end; base += 64) {
        int idx = base + lane;
        int sv = (idx < end) ? (int)csr_src[idx] : 0;
        int nv = min(64, end - base);
        int nf = nv >> 3;               // full 8-edge rounds
        int k = 0;
        for (; k + 2 <= nf; k += 2) {   // 2 gathers in flight
            int sA = __shfl(sv, 8 * k + g);
            int sB = __shfl(sv, 8 * k + 8 + g);
            if (qa) {
                uint4 vA = *(const uint4*)(XWs + (size_t)sA * F + 8 * q);
                uint4 vB = *(const uint4*)(XWs + (size_t)sB * F + 8 * q);
                float dA = EDGE_DINV ? dinv[sA] : 1.0f;
                float dB = EDGE_DINV ? dinv[sB] : 1.0f;
                if (EDGE_DINV) {
                    acc[0] = fmaf(bfLO(vA.x), dA, acc[0]); acc[1] = fmaf(bfHI(vA.x), dA, acc[1]);
                    acc[2] = fmaf(bfLO(vA.y), dA, acc[2]); acc[3] = fmaf(bfHI(vA.y), dA, acc[3]);
                    acc[4] = fmaf(bfLO(vA.z), dA, acc[4]); acc[5] = fmaf(bfHI(vA.z), dA, acc[5]);
                    acc[6] = fmaf(bfLO(vA.w), dA, acc[6]); acc[7] = fmaf(bfHI(vA.w), dA, acc[7]);
                    acc[0] = fmaf(bfLO(vB.x), dB, acc[0]); acc[1] = fmaf(bfHI(vB.x), dB, acc[1]);
                    acc[2] = fmaf(bfLO(vB.y), dB, acc[2]); acc[3] = fmaf(bfHI(vB.y), dB, acc[3]);
                    acc[4] = fmaf(bfLO(vB.z), dB, acc[4]); acc[5] = fmaf(bfHI(vB.z), dB, acc[5]);
                    acc[6] = fmaf(bfLO(vB.w), dB, acc[6]); acc[7] = fmaf(bfHI(vB.w), dB, acc[7]);
                } else {
                    acc[0] += bfLO(vA.x); acc[1] += bfHI(vA.x);
                    acc[2] += bfLO(vA.y); acc[3] += bfHI(vA.y);
                    acc[4] += bfLO(vA.z); acc[5] += bfHI(vA.z);
                    acc[6] += bfLO(vA.w); acc[7] += bfHI(vA.w);
                    acc[0] += bfLO(vB.x); acc[1] += bfHI(vB.x);
                    acc[2] += bfLO(vB.y); acc[3] += bfHI(vB.y);
                    acc[4] += bfLO(vB.z); acc[5] += bfHI(vB.z);
                    acc[6] += bfLO(vB.w); acc[7] += bfHI(vB.w);
                }
            }
        }
        for (; k < nf; ++k) {
            int s = __shfl(sv, 8 * k + g);
            if (qa) {
                uint4 v = *(const uint4*)(XWs + (size_t)s * F + 8 * q);
                float ds = EDGE_DINV ? dinv[s] : 1.0f;
                if (EDGE_DINV) {
                    acc[0] = fmaf(bfLO(v.x), ds, acc[0]); acc[1] = fmaf(bfHI(v.x), ds, acc[1]);
                    acc[2] = fmaf(bfLO(v.y), ds, acc[2]); acc[3] = fmaf(bfHI(v.y), ds, acc[3]);
                    acc[4] = fmaf(bfLO(v.z), ds, acc[4]); acc[5] = fmaf(bfHI(v.z), ds, acc[5]);
                    acc[6] = fmaf(bfLO(v.w), ds, acc[6]); acc[7] = fmaf(bfHI(v.w), ds, acc[7]);
                } else {
                    acc[0] += bfLO(v.x); acc[1] += bfHI(v.x);
                    acc[2] += bfLO(v.y); acc[3] += bfHI(v.y);
                    acc[4] += bfLO(v.z); acc[5] += bfHI(v.z);
                    acc[6] += bfLO(v.w); acc[7] += bfHI(v.w);
                }
            }
        }
        int rem = nv - (nf << 3);
        if (rem) {
            int jj = (nf << 3) + g;
            int s = __shfl(sv, jj);
            if (g < rem && qa) {
                uint4 v = *(const uint4*)(XWs + (size_t)s * F + 8 * q);
                float ds = EDGE_DINV ? dinv[s] : 1.0f;
                if (EDGE_DINV) {
                    acc[0] = fmaf(bfLO(v.x), ds, acc[0]); acc[1] = fmaf(bfHI(v.x), ds, acc[1]);
                    acc[2] = fmaf(bfLO(v.y), ds, acc[2]); acc[3] = fmaf(bfHI(v.y), ds, acc[3]);
                    acc[4] = fmaf(bfLO(v.z), ds, acc[4]); acc[5] = fmaf(bfHI(v.z), ds, acc[5]);
                    acc[6] = fmaf(bfLO(v.w), ds, acc[6]); acc[7] = fmaf(bfHI(v.w), ds, acc[7]);
                } else {
                    acc[0] += bfLO(v.x); acc[1] += bfHI(v.x);
                    acc[2] += bfLO(v.y); acc[3] += bfHI(v.y);
                    acc[4] += bfLO(v.z); acc[5] += bfHI(v.z);
                    acc[6] += bfLO(v.w); acc[7] += bfHI(v.w);
                }
            }
        }
    }

#pragma unroll
    for (int mask = 8; mask <= 32; mask <<= 1) {
#pragma unroll
        for (int t = 0; t < 8; ++t) acc[t] += __shfl_xor(acc[t], mask);
    }

    if (g == 0 && qa) {
        uint4 sv4 = *(const uint4*)(XWs + (size_t)d * F + 8 * q);
        float self[8] = { bfLO(sv4.x), bfHI(sv4.x), bfLO(sv4.y), bfHI(sv4.y),
                          bfLO(sv4.z), bfHI(sv4.z), bfLO(sv4.w), bfHI(sv4.w) };
        float dv = dinv[d];
        float ss = EDGE_DINV ? dv : 1.0f;
        float o[8];
#pragma unroll
        for (int t = 0; t < 8; ++t) {
            o[t] = fmaf(acc[t] + self[t] * ss, dv, b[8 * q + t]);
            if (RELU) o[t] = fmaxf(o[t], 0.f);
        }
        if (OUTBF) {
            ushort8v ov;
#pragma unroll
            for (int t = 0; t < 8; ++t) ov[t] = f2bf(o[t]);
            *(ushort8v*)((unsigned short*)outp + (size_t)d * F + 8 * q) = ov;
        } else {
            float4 o0 = { o[0], o[1], o[2], o[3] };
            float4 o1 = { o[4], o[5], o[6], o[7] };
            *(float4*)((float*)outp + (size_t)d * F + 8 * q)     = o0;
            *(float4*)((float*)outp + (size_t)d * F + 8 * q + 4) = o1;
        }
    }
}

extern "C" void kernel_launch(void* const* d_in, const int* in_sizes, int n_in,
                              void* d_out, int out_size, void* d_ws, size_t ws_size,
                              hipStream_t stream) {
    const float* x  = (const float*)d_in[0];
    const int*   ei = (const int*)d_in[1];
    const float* W1 = (const float*)d_in[2];
    const float* b1 = (const float*)d_in[3];
    const float* W2 = (const float*)d_in[4];
    const float* b2 = (const float*)d_in[5];
    const float* W3 = (const float*)d_in[6];
    const float* b3 = (const float*)d_in[7];
    float* out = (float*)d_out;

    const int* src = ei;
    const int* dst = ei + NEDGE;

    char* p = (char*)d_ws;
    auto alloc = [&](size_t bytes) { char* r = p; p += (bytes + 255) & ~size_t(255); return r; };
    unsigned int* bucketed = (unsigned int*)alloc((size_t)NEDGE * 4);
    int*   hist_g     = (int*)  alloc(NBUCKET * 256 * 4);
    int*   colsum     = (int*)  alloc(NBUCKET * 4);
    int*   rowstart   = (int*)  alloc((NNODE + 1) * 4);
    unsigned short* csr_src = (unsigned short*)alloc((size_t)NEDGE * 2);
    float* dinvp      = (float*)alloc(NNODE * 4);
    unsigned short* XWs = (unsigned short*)alloc((size_t)NNODE * 64 * 2 + 256);
    unsigned short* H1  = (unsigned short*)alloc((size_t)NNODE * 64 * 2 + 256);
    unsigned short* H2  = (unsigned short*)alloc((size_t)NNODE * 64 * 2 + 256);

    const int B = 256;
    const int gGemm = (NNODE + 63) / 64;          // 782
    const int gAgg  = (NNODE + 3) / 4;            // 12500

    // hist ∥ GEMM1(raw) -> scan+scatter (merged) -> fine CSR
    k_hist_gemm1  <<<256 + G1BLK, B, 0, stream>>>(dst, hist_g, x, W1, XWs);
    k_scan_scatter<<<256, B, 0, stream>>>(src, dst, hist_g, colsum, bucketed);
    k_bucketB2    <<<NBUCKET, B, 0, stream>>>(bucketed, colsum, rowstart, csr_src, dinvp);

    // layer 1 aggregate: raw rows -> per-edge dinv
    k_aggregate<64, true, true, true><<<gAgg, B, 0, stream>>>(XWs, rowstart, csr_src, dinvp, b1, H1);

    // layer 2: 64 -> 64, relu
    k_gemm_prescale<64, 64><<<gGemm, B, 0, stream>>>(H1, W2, dinvp, XWs);
    k_aggregate<64, true, true, false><<<gAgg, B, 0, stream>>>(XWs, rowstart, csr_src, dinvp, b2, H2);

    // layer 3: 64 -> 40, no act, f32 out
    k_gemm_prescale<64, 40><<<gGemm, B, 0, stream>>>(H2, W3, dinvp, XWs);
    k_aggregate<40, false, false, false><<<gAgg, B, 0, stream>>>(XWs, rowstart, csr_src, dinvp, b3, out);
}

// Round 19
// 150.144 us; speedup vs baseline: 1.0265x; 1.0265x over previous
//
#include <hip/hip_runtime.h>

#define NNODE 50000
#define NEDGE 800000
#define NBUCKET 196         // ceil(50000 / 256), bucket = dst >> 8
#define NPB 256             // nodes per bucket
#define EPB 3125            // NEDGE / 256 edges per producer block
#define G1BLK 782           // ceil(50000/64) GEMM1 tiles

typedef __attribute__((ext_vector_type(8))) unsigned short ushort8v;

__device__ inline unsigned short f2bf(float f) {           // round-to-nearest-even
    unsigned int u = __float_as_uint(f);
    u += 0x7FFFu + ((u >> 16) & 1u);
    return (unsigned short)(u >> 16);
}
__device__ inline float bf2f(unsigned short h) {
    return __uint_as_float((unsigned int)h << 16);
}
__device__ inline float bfLO(unsigned int u) { return __uint_as_float(u << 16); }
__device__ inline float bfHI(unsigned int u) { return __uint_as_float(u & 0xFFFF0000u); }

// ========== merged: edge histogram (blocks 0..255) ∥ GEMM1 (256..1037) =====
// Fully independent (GEMM1 writes RAW XW, no dinv dependency).

__global__ __launch_bounds__(256)
void k_hist_gemm1(const int* __restrict__ dst, int* __restrict__ hist_g,
                  const float* __restrict__ x, const float* __restrict__ W1,
                  unsigned short* __restrict__ XWs) {
    __shared__ float Xt[128 * 68];
    __shared__ float Ws[128 * 64];
    __shared__ int h[NBUCKET];
    const int tid = threadIdx.x, bid = blockIdx.x;

    if (bid < 256) {                      // ---- histogram chunk ----
        const int e0 = bid * EPB;
        if (tid < NBUCKET) h[tid] = 0;
        __syncthreads();
        for (int i = tid; i < EPB; i += 256)
            atomicAdd(&h[dst[e0 + i] >> 8], 1);
        __syncthreads();
        if (tid < NBUCKET) hist_g[tid * 256 + bid] = h[tid];
        return;
    }

    // ---- GEMM1 tile: 64 rows x 64 cols, FIN=128, RAW output ----
    const int r0 = (bid - 256) * 64;

    for (int idx = tid; idx < 128 * 64; idx += 256)
        Ws[idx] = W1[idx];

    for (int idx = tid; idx < 64 * 32; idx += 256) {
        int r_lo = idx & 7;
        int c = (idx >> 3) & 31;
        int r = ((idx >> 8) << 3) + r_lo;
        int rr = r0 + r; if (rr >= NNODE) rr = NNODE - 1;
        float4 v = *(const float4*)(x + (size_t)rr * 128 + c * 4);
        Xt[(4 * c + 0) * 68 + r] = v.x;
        Xt[(4 * c + 1) * 68 + r] = v.y;
        Xt[(4 * c + 2) * 68 + r] = v.z;
        Xt[(4 * c + 3) * 68 + r] = v.w;
    }
    __syncthreads();

    const int cg = tid & 15;
    const int rg = tid >> 4;

    float acc[4][4] = {};
#pragma unroll 4
    for (int k = 0; k < 128; ++k) {
        float4 xv = *(const float4*)&Xt[k * 68 + 4 * rg];
        float4 wv = *(const float4*)&Ws[k * 64 + 4 * cg];
#pragma unroll
        for (int i = 0; i < 4; ++i) {
            float xi = (i == 0) ? xv.x : (i == 1) ? xv.y : (i == 2) ? xv.z : xv.w;
            acc[i][0] = fmaf(xi, wv.x, acc[i][0]);
            acc[i][1] = fmaf(xi, wv.y, acc[i][1]);
            acc[i][2] = fmaf(xi, wv.z, acc[i][2]);
            acc[i][3] = fmaf(xi, wv.w, acc[i][3]);
        }
    }

#pragma unroll
    for (int i = 0; i < 4; ++i) {
        int row = r0 + 4 * rg + i;
        if (row < NNODE) {
            ushort4 o = { f2bf(acc[i][0]), f2bf(acc[i][1]), f2bf(acc[i][2]), f2bf(acc[i][3]) };
            *(ushort4*)(XWs + (size_t)row * 64 + 4 * cg) = o;
        }
    }
}

// ---------------- CSR build rest (R13-proven) ----------------

__global__ __launch_bounds__(256) void k_scanA1(const int* __restrict__ hist_g, int* __restrict__ base_g,
                                                int* __restrict__ colsum) {
    __shared__ int s[256];
    const int b = blockIdx.x, t = threadIdx.x;
    int v = hist_g[b * 256 + t];
    s[t] = v;
    __syncthreads();
#pragma unroll
    for (int off = 1; off < 256; off <<= 1) {
        int a = (t >= off) ? s[t - off] : 0;
        __syncthreads();
        s[t] += a;
        __syncthreads();
    }
    base_g[b * 256 + t] = s[t] - v;           // exclusive
    if (t == 255) colsum[b] = s[t];
}

__device__ inline void scan_colsum(const int* __restrict__ colsum, int* cs, int tid) {
    cs[tid] = (tid < NBUCKET) ? colsum[tid] : 0;
    __syncthreads();
#pragma unroll
    for (int off = 1; off < 256; off <<= 1) {
        int a = (tid >= off) ? cs[tid - off] : 0;
        __syncthreads();
        cs[tid] += a;
        __syncthreads();
    }
}

__global__ __launch_bounds__(256) void k_scatterA(const int* __restrict__ src, const int* __restrict__ dst,
                          const int* __restrict__ base_g, const int* __restrict__ colsum,
                          unsigned int* __restrict__ bucketed) {
    __shared__ int cs[256];
    __shared__ int cur[NBUCKET];
    const int tid = threadIdx.x, pb = blockIdx.x, e0 = pb * EPB;
    scan_colsum(colsum, cs, tid);
    if (tid < NBUCKET) {
        int bb = (tid == 0) ? 0 : cs[tid - 1];
        cur[tid] = bb + base_g[tid * 256 + pb];
    }
    __syncthreads();
    for (int i = tid; i < EPB; i += 256) {
        int d = dst[e0 + i], s = src[e0 + i];
        int pos = atomicAdd(&cur[d >> 8], 1);
        bucketed[pos] = ((unsigned int)d << 16) | (unsigned int)s;
    }
}

__global__ __launch_bounds__(256) void k_bucketB2(const unsigned int* __restrict__ bucketed,
                          const int* __restrict__ colsum, int* __restrict__ rowstart,
                          unsigned short* __restrict__ csr_src, float* __restrict__ dinv) {
    __shared__ int cs[256];
    __shared__ int cnt[NPB];
    __shared__ int ex[NPB];
    __shared__ int cur[NPB];
    const int tid = threadIdx.x, b = blockIdx.x;
    scan_colsum(colsum, cs, tid);
    const int base_out = (b == 0) ? 0 : cs[b - 1];
    const int end_out  = cs[b];

    cnt[tid] = 0;
    __syncthreads();
    for (int i = base_out + tid; i < end_out; i += 256)
        atomicAdd(&cnt[(bucketed[i] >> 16) & 255], 1);
    __syncthreads();

    int v = cnt[tid];
    ex[tid] = v;
    __syncthreads();
#pragma unroll
    for (int off = 1; off < 256; off <<= 1) {
        int a = (tid >= off) ? ex[tid - off] : 0;
        __syncthreads();
        ex[tid] += a;
        __syncthreads();
    }
    int excl = ex[tid] - v;
    int node = (b << 8) + tid;
    cur[tid] = base_out + excl;
    if (node < NNODE) {
        rowstart[node] = base_out + excl;
        dinv[node] = rsqrtf((float)v + 1.0f);
    }
    if (b == 0 && tid == 0) rowstart[NNODE] = NEDGE;
    __syncthreads();

    for (int i = base_out + tid; i < end_out; i += 256) {
        unsigned int u = bucketed[i];
        int pos = atomicAdd(&cur[(u >> 16) & 255], 1);
        csr_src[pos] = (unsigned short)(u & 0xFFFFu);
    }
}

// ---------------- GEMM + prescale (layers 2,3): bf16 in, bf16 out ----------

template<int FIN, int FOUT>
__launch_bounds__(256)
__global__ void k_gemm_prescale(const unsigned short* __restrict__ X, const float* __restrict__ W,
                                const float* __restrict__ dinv, unsigned short* __restrict__ XWs) {
    __shared__ float Xt[FIN * 68];
    __shared__ float Ws[FIN * 64];

    const int tid = threadIdx.x;
    const int r0 = blockIdx.x * 64;

    for (int idx = tid; idx < FIN * 64; idx += 256) {
        int k = idx >> 6, c = idx & 63;
        Ws[idx] = (c < FOUT) ? W[k * FOUT + c] : 0.0f;
    }

    constexpr int CH = FIN / 8;
    constexpr int CSH = (FIN == 128) ? 4 : 3;
    for (int idx = tid; idx < 64 * CH; idx += 256) {
        int r_lo = idx & 7;
        int c = (idx >> 3) & (CH - 1);
        int r = ((idx >> (3 + CSH)) << 3) + r_lo;
        int rr = r0 + r; if (rr >= NNODE) rr = NNODE - 1;
        ushort8v v = *(const ushort8v*)(X + (size_t)rr * FIN + c * 8);
#pragma unroll
        for (int t = 0; t < 8; ++t)
            Xt[(8 * c + t) * 68 + r] = bf2f(v[t]);
    }
    __syncthreads();

    const int cg = tid & 15;
    const int rg = tid >> 4;

    float acc[4][4] = {};
#pragma unroll 4
    for (int k = 0; k < FIN; ++k) {
        float4 xv = *(const float4*)&Xt[k * 68 + 4 * rg];
        float4 wv = *(const float4*)&Ws[k * 64 + 4 * cg];
#pragma unroll
        for (int i = 0; i < 4; ++i) {
            float xi = (i == 0) ? xv.x : (i == 1) ? xv.y : (i == 2) ? xv.z : xv.w;
            acc[i][0] = fmaf(xi, wv.x, acc[i][0]);
            acc[i][1] = fmaf(xi, wv.y, acc[i][1]);
            acc[i][2] = fmaf(xi, wv.z, acc[i][2]);
            acc[i][3] = fmaf(xi, wv.w, acc[i][3]);
        }
    }

    if (4 * cg + 4 <= FOUT) {
#pragma unroll
        for (int i = 0; i < 4; ++i) {
            int row = r0 + 4 * rg + i;
            if (row < NNODE) {
                float dv = dinv[row];
                ushort4 o = { f2bf(acc[i][0] * dv), f2bf(acc[i][1] * dv),
                              f2bf(acc[i][2] * dv), f2bf(acc[i][3] * dv) };
                *(ushort4*)(XWs + (size_t)row * FOUT + 4 * cg) = o;
            }
        }
    }
}

// ---------------- CSR aggregate + finalize: 2-deep MLP unroll --------------

template<int F, bool RELU, bool OUTBF, bool EDGE_DINV>
__launch_bounds__(256)
__global__ void k_aggregate(const unsigned short* __restrict__ XWs, const int* __restrict__ rowstart,
                            const unsigned short* __restrict__ csr_src, const float* __restrict__ dinv,
                            const float* __restrict__ b, void* __restrict__ outp) {
    constexpr int NQ = F / 8;
    const int wid  = threadIdx.x >> 6;
    const int lane = threadIdx.x & 63;
    const int g = lane >> 3;
    const int q = lane & 7;
    const int d = blockIdx.x * 4 + wid;
    if (d >= NNODE) return;

    const int beg = rowstart[d];
    const int end = rowstart[d + 1];
    const bool qa = (q < NQ);

    float acc[8] = {};

    for (int base = beg; base < end; base += 64) {
        int idx = base + lane;
        int sv = (idx < end) ? (int)csr_src[idx] : 0;
        int nv = min(64, end - base);
        int nf = nv >> 3;               // full 8-edge rounds
        int k = 0;
        for (; k + 2 <= nf; k += 2) {   // 2 gathers in flight
            int sA = __shfl(sv, 8 * k + g);
            int sB = __shfl(sv, 8 * k + 8 + g);
            if (qa) {
                uint4 vA = *(const uint4*)(XWs + (size_t)sA * F + 8 * q);
                uint4 vB = *(const uint4*)(XWs + (size_t)sB * F + 8 * q);
                float dA = EDGE_DINV ? dinv[sA] : 1.0f;
                float dB = EDGE_DINV ? dinv[sB] : 1.0f;
                if (EDGE_DINV) {
                    acc[0] = fmaf(bfLO(vA.x), dA, acc[0]); acc[1] = fmaf(bfHI(vA.x), dA, acc[1]);
                    acc[2] = fmaf(bfLO(vA.y), dA, acc[2]); acc[3] = fmaf(bfHI(vA.y), dA, acc[3]);
                    acc[4] = fmaf(bfLO(vA.z), dA, acc[4]); acc[5] = fmaf(bfHI(vA.z), dA, acc[5]);
                    acc[6] = fmaf(bfLO(vA.w), dA, acc[6]); acc[7] = fmaf(bfHI(vA.w), dA, acc[7]);
                    acc[0] = fmaf(bfLO(vB.x), dB, acc[0]); acc[1] = fmaf(bfHI(vB.x), dB, acc[1]);
                    acc[2] = fmaf(bfLO(vB.y), dB, acc[2]); acc[3] = fmaf(bfHI(vB.y), dB, acc[3]);
                    acc[4] = fmaf(bfLO(vB.z), dB, acc[4]); acc[5] = fmaf(bfHI(vB.z), dB, acc[5]);
                    acc[6] = fmaf(bfLO(vB.w), dB, acc[6]); acc[7] = fmaf(bfHI(vB.w), dB, acc[7]);
                } else {
                    acc[0] += bfLO(vA.x); acc[1] += bfHI(vA.x);
                    acc[2] += bfLO(vA.y); acc[3] += bfHI(vA.y);
                    acc[4] += bfLO(vA.z); acc[5] += bfHI(vA.z);
                    acc[6] += bfLO(vA.w); acc[7] += bfHI(vA.w);
                    acc[0] += bfLO(vB.x); acc[1] += bfHI(vB.x);
                    acc[2] += bfLO(vB.y); acc[3] += bfHI(vB.y);
                    acc[4] += bfLO(vB.z); acc[5] += bfHI(vB.z);
                    acc[6] += bfLO(vB.w); acc[7] += bfHI(vB.w);
                }
            }
        }
        for (; k < nf; ++k) {
            int s = __shfl(sv, 8 * k + g);
            if (qa) {
                uint4 v = *(const uint4*)(XWs + (size_t)s * F + 8 * q);
                float ds = EDGE_DINV ? dinv[s] : 1.0f;
                if (EDGE_DINV) {
                    acc[0] = fmaf(bfLO(v.x), ds, acc[0]); acc[1] = fmaf(bfHI(v.x), ds, acc[1]);
                    acc[2] = fmaf(bfLO(v.y), ds, acc[2]); acc[3] = fmaf(bfHI(v.y), ds, acc[3]);
                    acc[4] = fmaf(bfLO(v.z), ds, acc[4]); acc[5] = fmaf(bfHI(v.z), ds, acc[5]);
                    acc[6] = fmaf(bfLO(v.w), ds, acc[6]); acc[7] = fmaf(bfHI(v.w), ds, acc[7]);
                } else {
                    acc[0] += bfLO(v.x); acc[1] += bfHI(v.x);
                    acc[2] += bfLO(v.y); acc[3] += bfHI(v.y);
                    acc[4] += bfLO(v.z); acc[5] += bfHI(v.z);
                    acc[6] += bfLO(v.w); acc[7] += bfHI(v.w);
                }
            }
        }
        int rem = nv - (nf << 3);
        if (rem) {
            int jj = (nf << 3) + g;
            int s = __shfl(sv, jj);
            if (g < rem && qa) {
                uint4 v = *(const uint4*)(XWs + (size_t)s * F + 8 * q);
                float ds = EDGE_DINV ? dinv[s] : 1.0f;
                if (EDGE_DINV) {
                    acc[0] = fmaf(bfLO(v.x), ds, acc[0]); acc[1] = fmaf(bfHI(v.x), ds, acc[1]);
                    acc[2] = fmaf(bfLO(v.y), ds, acc[2]); acc[3] = fmaf(bfHI(v.y), ds, acc[3]);
                    acc[4] = fmaf(bfLO(v.z), ds, acc[4]); acc[5] = fmaf(bfHI(v.z), ds, acc[5]);
                    acc[6] = fmaf(bfLO(v.w), ds, acc[6]); acc[7] = fmaf(bfHI(v.w), ds, acc[7]);
                } else {
                    acc[0] += bfLO(v.x); acc[1] += bfHI(v.x);
                    acc[2] += bfLO(v.y); acc[3] += bfHI(v.y);
                    acc[4] += bfLO(v.z); acc[5] += bfHI(v.z);
                    acc[6] += bfLO(v.w); acc[7] += bfHI(v.w);
                }
            }
        }
    }

#pragma unroll
    for (int mask = 8; mask <= 32; mask <<= 1) {
#pragma unroll
        for (int t = 0; t < 8; ++t) acc[t] += __shfl_xor(acc[t], mask);
    }

    if (g == 0 && qa) {
        uint4 sv4 = *(const uint4*)(XWs + (size_t)d * F + 8 * q);
        float self[8] = { bfLO(sv4.x), bfHI(sv4.x), bfLO(sv4.y), bfHI(sv4.y),
                          bfLO(sv4.z), bfHI(sv4.z), bfLO(sv4.w), bfHI(sv4.w) };
        float dv = dinv[d];
        float ss = EDGE_DINV ? dv : 1.0f;
        float o[8];
#pragma unroll
        for (int t = 0; t < 8; ++t) {
            o[t] = fmaf(acc[t] + self[t] * ss, dv, b[8 * q + t]);
            if (RELU) o[t] = fmaxf(o[t], 0.f);
        }
        if (OUTBF) {
            ushort8v ov;
#pragma unroll
            for (int t = 0; t < 8; ++t) ov[t] = f2bf(o[t]);
            *(ushort8v*)((unsigned short*)outp + (size_t)d * F + 8 * q) = ov;
        } else {
            float4 o0 = { o[0], o[1], o[2], o[3] };
            float4 o1 = { o[4], o[5], o[6], o[7] };
            *(float4*)((float*)outp + (size_t)d * F + 8 * q)     = o0;
            *(float4*)((float*)outp + (size_t)d * F + 8 * q + 4) = o1;
        }
    }
}

extern "C" void kernel_launch(void* const* d_in, const int* in_sizes, int n_in,
                              void* d_out, int out_size, void* d_ws, size_t ws_size,
                              hipStream_t stream) {
    const float* x  = (const float*)d_in[0];
    const int*   ei = (const int*)d_in[1];
    const float* W1 = (const float*)d_in[2];
    const float* b1 = (const float*)d_in[3];
    const float* W2 = (const float*)d_in[4];
    const float* b2 = (const float*)d_in[5];
    const float* W3 = (const float*)d_in[6];
    const float* b3 = (const float*)d_in[7];
    float* out = (float*)d_out;

    const int* src = ei;
    const int* dst = ei + NEDGE;

    char* p = (char*)d_ws;
    auto alloc = [&](size_t bytes) { char* r = p; p += (bytes + 255) & ~size_t(255); return r; };
    unsigned int* bucketed = (unsigned int*)alloc((size_t)NEDGE * 4);
    int*   hist_g     = (int*)  alloc(NBUCKET * 256 * 4);
    int*   base_g     = (int*)  alloc(NBUCKET * 256 * 4);
    int*   colsum     = (int*)  alloc(NBUCKET * 4);
    int*   rowstart   = (int*)  alloc((NNODE + 1) * 4);
    unsigned short* csr_src = (unsigned short*)alloc((size_t)NEDGE * 2);
    float* dinvp      = (float*)alloc(NNODE * 4);
    unsigned short* XWs = (unsigned short*)alloc((size_t)NNODE * 64 * 2 + 256);
    unsigned short* H1  = (unsigned short*)alloc((size_t)NNODE * 64 * 2 + 256);
    unsigned short* H2  = (unsigned short*)alloc((size_t)NNODE * 64 * 2 + 256);

    const int B = 256;
    const int gGemm = (NNODE + 63) / 64;          // 782
    const int gAgg  = (NNODE + 3) / 4;            // 12500

    // hist ∥ GEMM1(raw) in one launch, then CSR chain
    k_hist_gemm1<<<256 + G1BLK, B, 0, stream>>>(dst, hist_g, x, W1, XWs);
    k_scanA1  <<<NBUCKET, B, 0, stream>>>(hist_g, base_g, colsum);
    k_scatterA<<<256, B, 0, stream>>>(src, dst, base_g, colsum, bucketed);
    k_bucketB2<<<NBUCKET, B, 0, stream>>>(bucketed, colsum, rowstart, csr_src, dinvp);

    // layer 1 aggregate: raw rows -> per-edge dinv
    k_aggregate<64, true, true, true><<<gAgg, B, 0, stream>>>(XWs, rowstart, csr_src, dinvp, b1, H1);

    // layer 2: 64 -> 64, relu
    k_gemm_prescale<64, 64><<<gGemm, B, 0, stream>>>(H1, W2, dinvp, XWs);
    k_aggregate<64, true, true, false><<<gAgg, B, 0, stream>>>(XWs, rowstart, csr_src, dinvp, b2, H2);

    // layer 3: 64 -> 40, no act, f32 out
    k_gemm_prescale<64, 40><<<gGemm, B, 0, stream>>>(H2, W3, dinvp, XWs);
    k_aggregate<40, false, false, false><<<gAgg, B, 0, stream>>>(XWs, rowstart, csr_src, dinvp, b3, out);
}